// Round 3
// baseline (125.689 us; speedup 1.0000x reference)
//
#include <hip/hip_runtime.h>

#define N_IN  1024
#define N_OUT 512
#define BATCH 128
#define M     (N_IN + 1)     // 1025 word lines (weights + bias line)

// ---------------- workspace layout (fast path) ----------------
// [0..3]   unsigned: max|weights| bits
// LS  at WS_LS_OFF: float2 LS[M][BATCH]   (l = log2(2|x|), s = sign)
// T   at WS_T_OFF : float4 T[M][N_OUT]    (lgp, lgn, ep, en)
#define WS_LS_OFF   1024
#define WS_LS_BYTES ((size_t)M * BATCH * 8)            // 1,049,600
#define WS_T_OFF    (WS_LS_OFF + WS_LS_BYTES)          // 1,050,624 (16B aligned)
#define WS_T_BYTES  ((size_t)M * N_OUT * 16)           // 8,396,800
#define WS_NEEDED   (WS_T_OFF + WS_T_BYTES)            // ~9.45 MB

// fast base-2 transcendentals: v_exp_f32 / v_log_f32
#if defined(__has_builtin)
#  if __has_builtin(__builtin_amdgcn_exp2f)
#    define FAST_EXP2(x) __builtin_amdgcn_exp2f(x)
#  endif
#  if __has_builtin(__builtin_amdgcn_logf)
#    define FAST_LOG2(x) __builtin_amdgcn_logf(x)
#  endif
#endif
#ifndef FAST_EXP2
#  define FAST_EXP2(x) exp2f(x)
#endif
#ifndef FAST_LOG2
#  define FAST_LOG2(x) log2f(x)
#endif

// ---------------------------------------------------------------------------
// Kernel 1: max|combined weights| -> ws[0] (IEEE bits, monotone for >= 0)
// ---------------------------------------------------------------------------
__global__ __launch_bounds__(256)
void maxred_kernel(const float4* __restrict__ wp4, const float4* __restrict__ wn4,
                   const float* __restrict__ bp, const float* __restrict__ bn,
                   unsigned* __restrict__ out)
{
    const int idx = blockIdx.x * 256 + threadIdx.x;     // grid 512 -> 131072 = NW/4
    const float4 a = wp4[idx];
    const float4 b = wn4[idx];
    float m = fmaxf(fmaxf(fmaxf(fabsf(a.x), fabsf(a.y)), fmaxf(fabsf(a.z), fabsf(a.w))),
                    fmaxf(fmaxf(fabsf(b.x), fabsf(b.y)), fmaxf(fabsf(b.z), fabsf(b.w))));
    if (idx < N_OUT)
        m = fmaxf(m, fmaxf(fabsf(bp[idx]), fabsf(bn[idx])));
    #pragma unroll
    for (int off = 32; off > 0; off >>= 1)
        m = fmaxf(m, __shfl_xor(m, off, 64));
    if ((threadIdx.x & 63) == 0)
        atomicMax(out, __float_as_uint(m));
}

// ---------------------------------------------------------------------------
// Kernel 2a: LS[i][b] = (log2(2|x[b,i]|), sign(x[b,i])); bias line -> (1, 1)
// ---------------------------------------------------------------------------
__global__ __launch_bounds__(256)
void prep_ls_kernel(const float* __restrict__ x, float2* __restrict__ LS)
{
    const int idx = blockIdx.x * 256 + threadIdx.x;     // over M*BATCH = 131200
    if (idx >= M * BATCH) return;
    const int i = idx >> 7;          // row (word line)
    const int b = idx & 127;         // batch
    float l = 1.0f, s = 1.0f;
    if (i < N_IN) {
        const float v = x[b * N_IN + i];
        s = (v > 0.0f) ? 1.0f : ((v < 0.0f) ? -1.0f : 0.0f);
        l = FAST_LOG2(2.0f * fabsf(v));   // -inf at v==0 -> exp2 = 0, s = 0
    }
    LS[idx] = make_float2(l, s);
}

// ---------------------------------------------------------------------------
// Kernel 2b: T[i][j] = (log2(gp), log2(gn), ep, en)
//   g = 0.5*w + 0.125*maxw (always > 0 here), e = log2(2.8 + 0.2*noise)
// ---------------------------------------------------------------------------
__global__ __launch_bounds__(256)
void prep_t_kernel(const float* __restrict__ wp, const float* __restrict__ wn,
                   const float* __restrict__ bp, const float* __restrict__ bn,
                   const float* __restrict__ nn, const unsigned* __restrict__ maxbits,
                   float4* __restrict__ T)
{
    const int idx = blockIdx.x * 256 + threadIdx.x;     // M*N_OUT = 524800 = 2050*256
    const int i = idx >> 9;
    const int j = idx & 511;
    const float gofs = 0.125f * __uint_as_float(*maxbits);
    const float wpv = (i < N_IN) ? wp[idx] : bp[j];
    const float wnv = (i < N_IN) ? wn[idx] : bn[j];
    const float2 np2 = reinterpret_cast<const float2*>(nn)[idx];  // nn[i][2j],[2j+1]
    const float gp = fmaf(0.5f, wpv, gofs);
    const float gn = fmaf(0.5f, wnv, gofs);
    T[idx] = make_float4(FAST_LOG2(gp), FAST_LOG2(gn),
                         FAST_LOG2(fmaf(0.2f, np2.x, 2.8f)),
                         FAST_LOG2(fmaf(0.2f, np2.y, 2.8f)));
}

// ---------------------------------------------------------------------------
// Kernel 3: main compute.  No LDS, no syncthreads.
//   acc[b] += s * (exp2(fma(ep,l,lgp)) - exp2(fma(en,l,lgn)))
// Block: 256 thr = 64 j-lanes x 4 waves, each wave owns 8 batches.
// Grid: 8 j-tiles x 4 b-tiles x 64 i-chunks (17 rows) = 2048 blocks.
// LS reads are wave-uniform (bslot via readfirstlane) -> scalar loads.
// ---------------------------------------------------------------------------
#define IC  64
#define CH2 17

__global__ __launch_bounds__(256)
void memristor_main(const float4* __restrict__ T, const float2* __restrict__ LS,
                    float* __restrict__ y)
{
    const int jlane = threadIdx.x & 63;
    const int bslot = __builtin_amdgcn_readfirstlane((int)(threadIdx.x >> 6));

    int bid = blockIdx.x;
    const int jt = bid & 7;  bid >>= 3;
    const int bt = bid & 3;  bid >>= 2;
    const int ic = bid;                       // 0..63

    const int i0 = ic * CH2;
    if (i0 >= M) return;                      // ic >= 61 empty
    const int iend = (i0 + CH2 < M) ? (i0 + CH2) : M;

    const int j  = jt * 64 + jlane;
    const int b0 = bt * 32 + bslot * 8;

    float acc[8];
    #pragma unroll
    for (int k = 0; k < 8; ++k) acc[k] = 0.0f;

    for (int i = i0; i < iend; ++i) {
        const float4 t4 = T[i * N_OUT + j];          // coalesced vector load
        const int lsbase = i * BATCH + b0;           // wave-uniform address
        #pragma unroll
        for (int k = 0; k < 8; ++k) {
            const float2 p = LS[lsbase + k];         // scalar (broadcast) load
            const float Ep = FAST_EXP2(fmaf(t4.z, p.x, t4.x));
            const float En = FAST_EXP2(fmaf(t4.w, p.x, t4.y));
            acc[k] = fmaf(p.y, Ep - En, acc[k]);
        }
    }

    #pragma unroll
    for (int k = 0; k < 8; ++k)
        atomicAdd(&y[(b0 + k) * N_OUT + j], acc[k]);
}

// ---------------------------------------------------------------------------
// Fallback (round-2 path) if ws_size is too small for LS+T staging.
// ---------------------------------------------------------------------------
#define JT 64
#define BT 32
#define BB 8
#define CH 65
#define J_TILES  (N_OUT / JT)
#define B_TILES  (BATCH / BT)
#define I_CHUNKS 16

__global__ __launch_bounds__(256)
void memristor_fallback(const float* __restrict__ x,  const float* __restrict__ wp,
                        const float* __restrict__ wn, const float* __restrict__ bp,
                        const float* __restrict__ bn, const float* __restrict__ nn,
                        const unsigned* __restrict__ maxw_bits,
                        float* __restrict__ y)
{
    __shared__ float2 lsbuf[BT][CH];
    const int jlane = threadIdx.x & 63;
    const int bslot = threadIdx.x >> 6;

    int bid = blockIdx.x;
    const int jt = bid & (J_TILES - 1);  bid >>= 3;
    const int bt = bid & (B_TILES - 1);  bid >>= 2;
    const int ic = bid;

    const int j0 = jt * JT;
    const int b0 = bt * BT;
    const int i0 = ic * CH;
    const int iend = min(i0 + CH, M);

    for (int idx = threadIdx.x; idx < BT * CH; idx += 256) {
        const int bb = idx / CH;
        const int ii = idx - bb * CH;
        const int i  = i0 + ii;
        float l = 1.0f, s = 1.0f;
        if (i < N_IN) {
            const float v = x[(b0 + bb) * N_IN + i];
            s = (v > 0.0f) ? 1.0f : ((v < 0.0f) ? -1.0f : 0.0f);
            l = FAST_LOG2(2.0f * fabsf(v));
        }
        lsbuf[bb][ii] = make_float2(l, s);
    }
    __syncthreads();

    const float maxw = __uint_as_float(*maxw_bits);
    const float gofs = 0.125f * maxw;
    const int   j    = j0 + jlane;

    float acc[BB];
    #pragma unroll
    for (int k = 0; k < BB; ++k) acc[k] = 0.0f;

    for (int i = i0; i < iend; ++i) {
        float wpv, wnv;
        if (i < N_IN) { wpv = wp[i * N_OUT + j]; wnv = wn[i * N_OUT + j]; }
        else          { wpv = bp[j];             wnv = bn[j]; }
        const float2 np2 = *reinterpret_cast<const float2*>(&nn[i * (2 * N_OUT) + 2 * j]);
        const float ep = FAST_LOG2(fmaf(0.2f, np2.x, 2.8f));
        const float en = FAST_LOG2(fmaf(0.2f, np2.y, 2.8f));
        const float gp = fmaf(0.5f, wpv, gofs);
        const float gn = fmaf(0.5f, wnv, gofs);
        const int   ii = i - i0;
        #pragma unroll
        for (int k = 0; k < BB; ++k) {
            const float2 lsv = lsbuf[bslot * BB + k][ii];
            const float Ep = FAST_EXP2(ep * lsv.x);
            const float En = FAST_EXP2(en * lsv.x);
            acc[k] = fmaf(lsv.y, fmaf(gp, Ep, -(gn * En)), acc[k]);
        }
    }
    #pragma unroll
    for (int k = 0; k < BB; ++k)
        atomicAdd(&y[(b0 + bslot * BB + k) * N_OUT + j], acc[k]);
}

// ---------------------------------------------------------------------------
extern "C" void kernel_launch(void* const* d_in, const int* in_sizes, int n_in,
                              void* d_out, int out_size, void* d_ws, size_t ws_size,
                              hipStream_t stream)
{
    const float* x  = (const float*)d_in[0];
    const float* wp = (const float*)d_in[1];
    const float* wn = (const float*)d_in[2];
    const float* bp = (const float*)d_in[3];
    const float* bn = (const float*)d_in[4];
    const float* nn = (const float*)d_in[5];
    float*    y     = (float*)d_out;
    unsigned* wsmax = (unsigned*)d_ws;

    (void)hipMemsetAsync(wsmax, 0, sizeof(unsigned), stream);
    (void)hipMemsetAsync(y, 0, (size_t)out_size * sizeof(float), stream);

    maxred_kernel<<<512, 256, 0, stream>>>((const float4*)wp, (const float4*)wn,
                                           bp, bn, wsmax);

    if (ws_size >= WS_NEEDED) {
        float2* LS = (float2*)((char*)d_ws + WS_LS_OFF);
        float4* T  = (float4*)((char*)d_ws + WS_T_OFF);
        prep_ls_kernel<<<(M * BATCH + 255) / 256, 256, 0, stream>>>(x, LS);
        prep_t_kernel<<<(M * N_OUT) / 256, 256, 0, stream>>>(wp, wn, bp, bn, nn,
                                                             wsmax, T);
        memristor_main<<<8 * 4 * IC, 256, 0, stream>>>(T, LS, y);
    } else {
        memristor_fallback<<<J_TILES * B_TILES * I_CHUNKS, 256, 0, stream>>>(
            x, wp, wn, bp, bn, nn, wsmax, y);
    }
}

// Round 4
// 99.109 us; speedup vs baseline: 1.2682x; 1.2682x over previous
//
#include <hip/hip_runtime.h>

#define N_IN  1024
#define N_OUT 512
#define BATCH 128
#define M     (N_IN + 1)     // 1025 word lines (weights + bias line)

// ---------------- workspace layout ----------------
// maxp[256] floats at offset 0 (per-block max|weights| partials)
// LS float2[M][BATCH] at offset 1024: (l = log2(2|x|), s = sign(x))
#define WS_MAXP_OFF 0
#define WS_LS_OFF   1024
#define WS_LS_BYTES ((size_t)M * BATCH * 8)           // 1,049,600
#define WS_NEEDED   (WS_LS_OFF + WS_LS_BYTES)         // ~1.05 MB

// fast base-2 transcendentals: v_exp_f32 / v_log_f32 (both base-2 on AMDGPU)
#if defined(__has_builtin)
#  if __has_builtin(__builtin_amdgcn_exp2f)
#    define FAST_EXP2(x) __builtin_amdgcn_exp2f(x)
#  endif
#  if __has_builtin(__builtin_amdgcn_logf)
#    define FAST_LOG2(x) __builtin_amdgcn_logf(x)
#  endif
#endif
#ifndef FAST_EXP2
#  define FAST_EXP2(x) exp2f(x)
#endif
#ifndef FAST_LOG2
#  define FAST_LOG2(x) log2f(x)
#endif

#define MAXRED_BLOCKS 256
#define PREP_BLOCKS   ((M * BATCH + 255) / 256)       // 513

// ---------------------------------------------------------------------------
// Kernel 1 (fused setup):
//   blocks [0,256):       maxp[bid] = block-max of |wp|,|wn| (+ biases in blk 0)
//   blocks [256,256+513): LS[i][b] = (log2(2|x[b,i]|), sign); bias row -> (1,1)
// ---------------------------------------------------------------------------
__global__ __launch_bounds__(256)
void setup_kernel(const float4* __restrict__ wp4, const float4* __restrict__ wn4,
                  const float* __restrict__ bp, const float* __restrict__ bn,
                  const float* __restrict__ x,
                  float* __restrict__ maxp, float2* __restrict__ LS)
{
    const int bid = blockIdx.x;
    if (bid < MAXRED_BLOCKS) {
        const int t = threadIdx.x;
        const int base = bid * 512;                  // float4 index; 131072 total
        float m = 0.0f;
        #pragma unroll
        for (int r = 0; r < 2; ++r) {
            const float4 a = wp4[base + r * 256 + t];
            const float4 b = wn4[base + r * 256 + t];
            m = fmaxf(m, fmaxf(fmaxf(fabsf(a.x), fabsf(a.y)),
                               fmaxf(fabsf(a.z), fabsf(a.w))));
            m = fmaxf(m, fmaxf(fmaxf(fabsf(b.x), fabsf(b.y)),
                               fmaxf(fabsf(b.z), fabsf(b.w))));
        }
        if (bid == 0) {
            m = fmaxf(m, fmaxf(fabsf(bp[t]), fabsf(bp[t + 256])));
            m = fmaxf(m, fmaxf(fabsf(bn[t]), fabsf(bn[t + 256])));
        }
        #pragma unroll
        for (int off = 32; off > 0; off >>= 1)
            m = fmaxf(m, __shfl_xor(m, off, 64));
        __shared__ float wred[4];
        const int wid = threadIdx.x >> 6;
        if ((threadIdx.x & 63) == 0) wred[wid] = m;
        __syncthreads();
        if (threadIdx.x == 0)
            maxp[bid] = fmaxf(fmaxf(wred[0], wred[1]), fmaxf(wred[2], wred[3]));
    } else {
        const int idx = (bid - MAXRED_BLOCKS) * 256 + threadIdx.x;
        if (idx >= M * BATCH) return;
        const int i = idx >> 7;                      // word line
        const int b = idx & 127;                     // batch
        float l = 1.0f, s = 1.0f;
        if (i < N_IN) {
            const float v = x[b * N_IN + i];
            s = (v > 0.0f) ? 1.0f : ((v < 0.0f) ? -1.0f : 0.0f);
            l = FAST_LOG2(2.0f * fabsf(v));          // -inf at v==0 -> exp2=0, s=0
        }
        LS[idx] = make_float2(l, s);
    }
}

// ---------------------------------------------------------------------------
// Kernel 2: fused main compute (no T table, no LDS, no syncthreads).
//   y[b,j] += s * ( gp*exp2(ep*l) - gn*exp2(en*l) )
//   gp/gn = 0.5*w + 0.125*maxw ; ep/en = log2(2.8 + 0.2*noise)
// Block: 256 thr = 64 j-lanes x 4 waves; each wave owns 8 batches.
// Grid: 8 j-tiles x 4 b-tiles x 61 i-chunks (17 rows) = 1952 blocks.
// maxw: each wave reduces maxp[256] at entry (~60 cy).
// ---------------------------------------------------------------------------
#define IC  61
#define CH2 17

__global__ __launch_bounds__(256)
void memristor_main(const float* __restrict__ wp, const float* __restrict__ wn,
                    const float* __restrict__ bp, const float* __restrict__ bn,
                    const float* __restrict__ nn, const float* __restrict__ maxp,
                    const float2* __restrict__ LS, float* __restrict__ y)
{
    const int jlane = threadIdx.x & 63;
    const int bslot = __builtin_amdgcn_readfirstlane((int)(threadIdx.x >> 6));

    // wave-wide reduction of the 256 max partials
    float m = fmaxf(fmaxf(maxp[jlane], maxp[jlane + 64]),
                    fmaxf(maxp[jlane + 128], maxp[jlane + 192]));
    #pragma unroll
    for (int off = 32; off > 0; off >>= 1)
        m = fmaxf(m, __shfl_xor(m, off, 64));
    const float gofs = 0.125f * __uint_as_float(
        __builtin_amdgcn_readfirstlane(__float_as_uint(m)));

    int bid = blockIdx.x;
    const int jt = bid & 7;
    const int bt = (bid >> 3) & 3;
    const int ic = bid >> 5;                  // 0..60

    const int i0   = ic * CH2;
    const int iend = (i0 + CH2 < M) ? (i0 + CH2) : M;
    const int j    = jt * 64 + jlane;
    const int b0   = bt * 32 + bslot * 8;

    float acc[8];
    #pragma unroll
    for (int k = 0; k < 8; ++k) acc[k] = 0.0f;

    for (int i = i0; i < iend; ++i) {
        float wpv, wnv;
        if (i < N_IN) {
            wpv = wp[i * N_OUT + j];
            wnv = wn[i * N_OUT + j];
        } else {
            wpv = bp[j];
            wnv = bn[j];
        }
        const float2 np2 = reinterpret_cast<const float2*>(nn)[i * N_OUT + j];
        const float ep = FAST_LOG2(fmaf(0.2f, np2.x, 2.8f));
        const float en = FAST_LOG2(fmaf(0.2f, np2.y, 2.8f));
        const float gp = fmaf(0.5f, wpv, gofs);
        const float gn = fmaf(0.5f, wnv, gofs);
        const int lsb = i * BATCH + b0;              // wave-uniform address
        #pragma unroll
        for (int k = 0; k < 8; ++k) {
            const float2 p = LS[lsb + k];            // scalar (broadcast) loads
            const float Ep = FAST_EXP2(ep * p.x);
            const float En = FAST_EXP2(en * p.x);
            acc[k] = fmaf(p.y, fmaf(gp, Ep, -(gn * En)), acc[k]);
        }
    }

    #pragma unroll
    for (int k = 0; k < 8; ++k)
        atomicAdd(&y[(b0 + k) * N_OUT + j], acc[k]);
}

// ---------------------------------------------------------------------------
extern "C" void kernel_launch(void* const* d_in, const int* in_sizes, int n_in,
                              void* d_out, int out_size, void* d_ws, size_t ws_size,
                              hipStream_t stream)
{
    const float* x  = (const float*)d_in[0];
    const float* wp = (const float*)d_in[1];
    const float* wn = (const float*)d_in[2];
    const float* bp = (const float*)d_in[3];
    const float* bn = (const float*)d_in[4];
    const float* nn = (const float*)d_in[5];
    float* y        = (float*)d_out;

    float*  maxp = (float*)((char*)d_ws + WS_MAXP_OFF);
    float2* LS   = (float2*)((char*)d_ws + WS_LS_OFF);

    // y accumulated via atomics -> zero-init (poisoned to 0xAA by harness)
    (void)hipMemsetAsync(y, 0, (size_t)out_size * sizeof(float), stream);

    setup_kernel<<<MAXRED_BLOCKS + PREP_BLOCKS, 256, 0, stream>>>(
        (const float4*)wp, (const float4*)wn, bp, bn, x, maxp, LS);

    memristor_main<<<8 * 4 * IC, 256, 0, stream>>>(wp, wn, bp, bn, nn,
                                                   maxp, LS, y);
}

// Round 5
// 91.965 us; speedup vs baseline: 1.3667x; 1.0777x over previous
//
#include <hip/hip_runtime.h>

#define N_IN  1024
#define N_OUT 512
#define BATCH 128
#define M     (N_IN + 1)     // 1025 word lines (weights + bias line)

// workspace: maxp[256] floats at offset 0 (per-block max|weights| partials)

// fast base-2 transcendentals: v_exp_f32 / v_log_f32 (both base-2 on AMDGPU)
#if defined(__has_builtin)
#  if __has_builtin(__builtin_amdgcn_exp2f)
#    define FAST_EXP2(x) __builtin_amdgcn_exp2f(x)
#  endif
#  if __has_builtin(__builtin_amdgcn_logf)
#    define FAST_LOG2(x) __builtin_amdgcn_logf(x)
#  endif
#endif
#ifndef FAST_EXP2
#  define FAST_EXP2(x) exp2f(x)
#endif
#ifndef FAST_LOG2
#  define FAST_LOG2(x) log2f(x)
#endif

// ---------------------------------------------------------------------------
// Kernel 1: per-block max|weights| partials -> maxp[256], and zero y.
// 256 blocks x 256 threads. Block 0 also covers the bias vectors.
// No atomics, no memsets needed.
// ---------------------------------------------------------------------------
__global__ __launch_bounds__(256)
void maxred_kernel(const float4* __restrict__ wp4, const float4* __restrict__ wn4,
                   const float* __restrict__ bp, const float* __restrict__ bn,
                   float* __restrict__ maxp, float* __restrict__ y)
{
    const int bid = blockIdx.x;
    const int t   = threadIdx.x;

    // zero my slice of y (65536 = 256 blocks * 256 threads)
    y[bid * 256 + t] = 0.0f;

    const int base = bid * 512;                  // float4 index; 131072 total
    float m = 0.0f;
    #pragma unroll
    for (int r = 0; r < 2; ++r) {
        const float4 a = wp4[base + r * 256 + t];
        const float4 b = wn4[base + r * 256 + t];
        m = fmaxf(m, fmaxf(fmaxf(fabsf(a.x), fabsf(a.y)),
                           fmaxf(fabsf(a.z), fabsf(a.w))));
        m = fmaxf(m, fmaxf(fmaxf(fabsf(b.x), fabsf(b.y)),
                           fmaxf(fabsf(b.z), fabsf(b.w))));
    }
    if (bid == 0) {
        m = fmaxf(m, fmaxf(fabsf(bp[t]), fabsf(bp[t + 256])));
        m = fmaxf(m, fmaxf(fabsf(bn[t]), fabsf(bn[t + 256])));
    }
    #pragma unroll
    for (int off = 32; off > 0; off >>= 1)
        m = fmaxf(m, __shfl_xor(m, off, 64));

    __shared__ float wred[4];
    const int wid = t >> 6;
    if ((t & 63) == 0) wred[wid] = m;
    __syncthreads();
    if (t == 0)
        maxp[bid] = fmaxf(fmaxf(wred[0], wred[1]), fmaxf(wred[2], wred[3]));
}

// ---------------------------------------------------------------------------
// Kernel 2: fused main compute.
//   y[b,j] += s * ( gp*exp2(ep*l) - gn*exp2(en*l) ),  l = log2(2|x|)
//   gp/gn = 0.5*w + 0.125*maxw ; ep/en = log2(2.8 + 0.2*noise)
// Block: 256 thr = 64 j-lanes x 4 waves; each wave owns 8 batches.
// Grid: 8 j-tiles x 4 b-tiles x 64 i-chunks (16 rows each) = 2048 blocks
//       (8 blocks/CU -> full occupancy). Branch-free weight loop; the bias
//       word line is a closed-form epilogue on ic==63 (exp2(e*1) = n, no
//       transcendentals). x slice staged in LDS as (l, s).
// ---------------------------------------------------------------------------
#define CH 16
#define IC 64

__global__ __launch_bounds__(256)
void memristor_main(const float* __restrict__ x,  const float* __restrict__ wp,
                    const float* __restrict__ wn, const float* __restrict__ bp,
                    const float* __restrict__ bn, const float* __restrict__ nn,
                    const float* __restrict__ maxp, float* __restrict__ y)
{
    __shared__ float2 lsbuf[32][CH];             // [batch-in-tile][row-in-chunk]

    const int jlane = threadIdx.x & 63;
    const int bslot = __builtin_amdgcn_readfirstlane((int)(threadIdx.x >> 6));

    const int bid = blockIdx.x;
    const int jt  = bid & 7;
    const int bt  = (bid >> 3) & 3;
    const int ic  = bid >> 5;                    // 0..63

    const int i0 = ic * CH;
    const int j  = jt * 64 + jlane;
    const int b0 = bt * 32;

    // ---- stage (l = log2(2|x|), s = sign) for 32 batches x 16 rows ----
    {
        const int ii = threadIdx.x & 15;         // row in chunk
        const int bb = threadIdx.x >> 4;         // 0..15, second pass +16
        #pragma unroll
        for (int r = 0; r < 2; ++r) {
            const int bbb = bb + r * 16;
            const float v = x[(b0 + bbb) * N_IN + i0 + ii];
            const float s = (v > 0.0f) ? 1.0f : ((v < 0.0f) ? -1.0f : 0.0f);
            const float l = FAST_LOG2(2.0f * fabsf(v));  // -inf at 0 -> exp2=0
            lsbuf[bbb][ii] = make_float2(l, s);
        }
    }

    // ---- global max|w| from the 256 partials (wave-local reduce) ----
    float m = fmaxf(fmaxf(maxp[jlane], maxp[jlane + 64]),
                    fmaxf(maxp[jlane + 128], maxp[jlane + 192]));
    #pragma unroll
    for (int off = 32; off > 0; off >>= 1)
        m = fmaxf(m, __shfl_xor(m, off, 64));
    const float gofs = 0.125f * __uint_as_float(
        __builtin_amdgcn_readfirstlane(__float_as_uint(m)));

    __syncthreads();

    float acc[8];
    #pragma unroll
    for (int k = 0; k < 8; ++k) acc[k] = 0.0f;

    const float*  wprow = wp + (size_t)i0 * N_OUT + j;
    const float*  wnrow = wn + (size_t)i0 * N_OUT + j;
    const float2* nnrow = (const float2*)nn + (size_t)i0 * N_OUT + j;

    #pragma unroll 4
    for (int ii = 0; ii < CH; ++ii) {
        const float wpv = wprow[ii * N_OUT];
        const float wnv = wnrow[ii * N_OUT];
        const float2 np2 = nnrow[ii * N_OUT];
        const float ep = FAST_LOG2(fmaf(0.2f, np2.x, 2.8f));
        const float en = FAST_LOG2(fmaf(0.2f, np2.y, 2.8f));
        const float gp = fmaf(0.5f, wpv, gofs);
        const float gn = fmaf(0.5f, wnv, gofs);
        #pragma unroll
        for (int k = 0; k < 8; ++k) {
            const float2 p = lsbuf[bslot * 8 + k][ii];   // uniform addr: broadcast
            const float Ep = FAST_EXP2(ep * p.x);
            const float En = FAST_EXP2(en * p.x);
            acc[k] = fmaf(p.y, fmaf(gp, Ep, -(gn * En)), acc[k]);
        }
    }

    // ---- bias word line (i = N_IN): l = 1, s = 1 -> exp2(e*1) = n exactly ----
    if (ic == IC - 1) {
        const float2 np2 = ((const float2*)nn)[(size_t)N_IN * N_OUT + j];
        const float npp = fmaf(0.2f, np2.x, 2.8f);
        const float npn = fmaf(0.2f, np2.y, 2.8f);
        const float gp = fmaf(0.5f, bp[j], gofs);
        const float gn = fmaf(0.5f, bn[j], gofs);
        const float t  = fmaf(gp, npp, -(gn * npn));
        #pragma unroll
        for (int k = 0; k < 8; ++k) acc[k] += t;
    }

    #pragma unroll
    for (int k = 0; k < 8; ++k)
        atomicAdd(&y[(b0 + bslot * 8 + k) * N_OUT + j], acc[k]);
}

// ---------------------------------------------------------------------------
extern "C" void kernel_launch(void* const* d_in, const int* in_sizes, int n_in,
                              void* d_out, int out_size, void* d_ws, size_t ws_size,
                              hipStream_t stream)
{
    const float* x  = (const float*)d_in[0];
    const float* wp = (const float*)d_in[1];
    const float* wn = (const float*)d_in[2];
    const float* bp = (const float*)d_in[3];
    const float* bn = (const float*)d_in[4];
    const float* nn = (const float*)d_in[5];
    float* y        = (float*)d_out;
    float* maxp     = (float*)d_ws;

    maxred_kernel<<<256, 256, 0, stream>>>((const float4*)wp, (const float4*)wn,
                                           bp, bn, maxp, y);

    memristor_main<<<8 * 4 * IC, 256, 0, stream>>>(x, wp, wn, bp, bn, nn,
                                                   maxp, y);
}